// Round 4
// baseline (1143.360 us; speedup 1.0000x reference)
//
#include <hip/hip_runtime.h>
#include <cstdint>
#include <cstddef>

#define U_CNT 100000
#define I_CNT 50000
#define D_DIM 64
#define N_CNT (U_CNT + I_CNT)
#define NNZ_CNT 4000000
#define EPS_F 0.2f

// column-block sort parameters
#define CB_SHIFT 12                       // 4096 cols per block = 1 MB of x
#define NCB ((N_CNT >> CB_SHIFT) + 1)     // 37
#define KEYS ((size_t)N_CNT * NCB)        // 5,550,000
#define SCAN_TILE2 4096                   // 256 thr x 16 elems
#define N_TILES2 ((int)((KEYS + SCAN_TILE2 - 1) / SCAN_TILE2))   // 1356
#define KEYS_PAD ((size_t)N_TILES2 * SCAN_TILE2)                 // 5,554,176

// ---------------- key histogram: key = row*NCB + (col>>CB_SHIFT) ----------
__global__ void hist_key_kernel(const int* __restrict__ rows,
                                const int* __restrict__ cols,
                                int* __restrict__ keycnt) {
    int t = blockIdx.x * blockDim.x + threadIdx.x;
    if (t >= NNZ_CNT / 4) return;
    int4 r4 = ((const int4*)rows)[t];
    int4 c4 = ((const int4*)cols)[t];
    atomicAdd(&keycnt[(size_t)r4.x * NCB + (c4.x >> CB_SHIFT)], 1);
    atomicAdd(&keycnt[(size_t)r4.y * NCB + (c4.y >> CB_SHIFT)], 1);
    atomicAdd(&keycnt[(size_t)r4.z * NCB + (c4.z >> CB_SHIFT)], 1);
    atomicAdd(&keycnt[(size_t)r4.w * NCB + (c4.w >> CB_SHIFT)], 1);
}

// ---------------- scan stage 1: in-place exclusive scan of 4096-elem tiles
__global__ __launch_bounds__(256) void key_scan1(int* __restrict__ key,
                                                 int* __restrict__ tileSums) {
    __shared__ int lds[256];
    const int t = threadIdx.x;
    const size_t base = (size_t)blockIdx.x * SCAN_TILE2 + (size_t)t * 16;
    int v[16];
    #pragma unroll
    for (int q = 0; q < 4; ++q) {
        int4 x = ((const int4*)(key + base))[q];
        v[q * 4 + 0] = x.x; v[q * 4 + 1] = x.y; v[q * 4 + 2] = x.z; v[q * 4 + 3] = x.w;
    }
    int s = 0;
    #pragma unroll
    for (int j = 0; j < 16; ++j) s += v[j];
    lds[t] = s;
    __syncthreads();
    for (int off = 1; off < 256; off <<= 1) {
        int x = (t >= off) ? lds[t - off] : 0;
        __syncthreads();
        lds[t] += x;
        __syncthreads();
    }
    int ex = (t > 0) ? lds[t - 1] : 0;
    #pragma unroll
    for (int q = 0; q < 4; ++q) {
        int4 w;
        w.x = ex; ex += v[q * 4 + 0];
        w.y = ex; ex += v[q * 4 + 1];
        w.z = ex; ex += v[q * 4 + 2];
        w.w = ex; ex += v[q * 4 + 3];
        ((int4*)(key + base))[q] = w;
    }
    if (t == 255) tileSums[blockIdx.x] = lds[255];
}

// ---------------- scan stage 2: scan 1356 tile sums in one block ----------
__global__ __launch_bounds__(256) void key_scan2(const int* __restrict__ tileSums,
                                                 int* __restrict__ tileOffs) {
    __shared__ int lds[256];
    const int t = threadIdx.x;
    const int C = (N_TILES2 + 255) / 256;   // 6
    int v[8];
    int s = 0;
    for (int j = 0; j < C; ++j) {
        int i = t * C + j;
        v[j] = (i < N_TILES2) ? tileSums[i] : 0;
        s += v[j];
    }
    lds[t] = s;
    __syncthreads();
    for (int off = 1; off < 256; off <<= 1) {
        int x = (t >= off) ? lds[t - off] : 0;
        __syncthreads();
        lds[t] += x;
        __syncthreads();
    }
    int ex = (t > 0) ? lds[t - 1] : 0;
    for (int j = 0; j < C; ++j) {
        int i = t * C + j;
        if (i < N_TILES2) tileOffs[i] = ex;
        ex += v[j];
    }
}

// ---------------- scan stage 3: add tile offsets ----------------
__global__ __launch_bounds__(256) void key_scan3(int* __restrict__ key,
                                                 const int* __restrict__ tileOffs) {
    const int off = tileOffs[blockIdx.x];
    const size_t base = (size_t)blockIdx.x * SCAN_TILE2 + (size_t)threadIdx.x * 16;
    #pragma unroll
    for (int q = 0; q < 4; ++q) {
        int4 x = ((const int4*)(key + base))[q];
        x.x += off; x.y += off; x.z += off; x.w += off;
        ((int4*)(key + base))[q] = x;
    }
}

// ---------------- rowptr extraction (BEFORE scatter destroys keyptr) ------
__global__ void rowptr_kernel(const int* __restrict__ keyptr,
                              int* __restrict__ rowptr) {
    int r = blockIdx.x * blockDim.x + threadIdx.x;
    if (r < N_CNT) rowptr[r] = keyptr[(size_t)r * NCB];
    if (r == 0) rowptr[N_CNT] = NNZ_CNT;
}

// ---------------- scatter: keyptr doubles as cursor (destroyed) -----------
__global__ void scatter_key_kernel(const int* __restrict__ rows,
                                   const int* __restrict__ cols,
                                   const float* __restrict__ vals,
                                   int* __restrict__ keyptr,
                                   int2* __restrict__ cpack) {
    int t = blockIdx.x * blockDim.x + threadIdx.x;
    if (t >= NNZ_CNT / 4) return;
    int4   r4 = ((const int4*)rows)[t];
    int4   c4 = ((const int4*)cols)[t];
    float4 v4 = ((const float4*)vals)[t];
    int p;
    p = atomicAdd(&keyptr[(size_t)r4.x * NCB + (c4.x >> CB_SHIFT)], 1);
    cpack[p] = make_int2(c4.x, __float_as_int(v4.x));
    p = atomicAdd(&keyptr[(size_t)r4.y * NCB + (c4.y >> CB_SHIFT)], 1);
    cpack[p] = make_int2(c4.y, __float_as_int(v4.y));
    p = atomicAdd(&keyptr[(size_t)r4.z * NCB + (c4.z >> CB_SHIFT)], 1);
    cpack[p] = make_int2(c4.z, __float_as_int(v4.z));
    p = atomicAdd(&keyptr[(size_t)r4.w * NCB + (c4.w >> CB_SHIFT)], 1);
    cpack[p] = make_int2(c4.w, __float_as_int(v4.w));
}

__device__ __forceinline__ float sgnf(float x) {
    return (x > 0.f) ? 1.f : ((x < 0.f) ? -1.f : 0.f);
}

// ---------------- fused SpMM + noise + accumulate (unchanged) -------------
// 16 lanes per row (each lane owns a float4 of D=64); 4 rows per wave.
// Edges are now sorted by column block within each row -> all resident
// row-groups sweep x monotonically, keeping the gather window L2-resident.
template <int MODE>
__global__ __launch_bounds__(256) void layer_kernel(
    const int* __restrict__ rowptr, const int2* __restrict__ cpack,
    const float4* __restrict__ xin, const float4* __restrict__ ue4,
    const float4* __restrict__ ie4,
    const float4* __restrict__ noise_k, float4* __restrict__ xnext,
    float4* __restrict__ acc_out) {
    const int gl = threadIdx.x & 15;
    const int r  = blockIdx.x * 16 + (threadIdx.x >> 4);
    if (r >= N_CNT) return;
    const int start = rowptr[r];
    const int end   = rowptr[r + 1];

    float4 acc = make_float4(0.f, 0.f, 0.f, 0.f);
    #pragma unroll 4
    for (int e = start; e < end; ++e) {
        int2 p = cpack[e];
        float vj = __int_as_float(p.y);
        const float4* xb;
        if (MODE == 0) {
            xb = (p.x < U_CNT) ? (ue4 + (size_t)p.x * 16)
                               : (ie4 + (size_t)(p.x - U_CNT) * 16);
        } else {
            xb = xin + (size_t)p.x * 16;
        }
        float4 xr = xb[gl];
        acc.x += vj * xr.x;
        acc.y += vj * xr.y;
        acc.z += vj * xr.z;
        acc.w += vj * xr.w;
    }

    float4 nz = noise_k[(size_t)r * 16 + gl];
    float sq = nz.x * nz.x + nz.y * nz.y + nz.z * nz.z + nz.w * nz.w;
    #pragma unroll
    for (int off = 8; off > 0; off >>= 1) sq += __shfl_xor(sq, off);
    float inv = EPS_F / fmaxf(sqrtf(sq), 1e-12f);

    float4 ego;
    ego.x = acc.x + sgnf(acc.x) * nz.x * inv;
    ego.y = acc.y + sgnf(acc.y) * nz.y * inv;
    ego.z = acc.z + sgnf(acc.z) * nz.z * inv;
    ego.w = acc.w + sgnf(acc.w) * nz.w * inv;

    size_t oi = (size_t)r * 16 + gl;
    if (MODE == 0) {
        xnext[oi] = ego;
        acc_out[oi] = ego;
    } else if (MODE == 1) {
        xnext[oi] = ego;
        float4 a = acc_out[oi];
        a.x += ego.x; a.y += ego.y; a.z += ego.z; a.w += ego.w;
        acc_out[oi] = a;
    } else {
        float4 a = acc_out[oi];
        a.x = (a.x + ego.x) * (1.f / 3.f);
        a.y = (a.y + ego.y) * (1.f / 3.f);
        a.z = (a.z + ego.z) * (1.f / 3.f);
        a.w = (a.w + ego.w) * (1.f / 3.f);
        acc_out[oi] = a;
    }
}

extern "C" void kernel_launch(void* const* d_in, const int* in_sizes, int n_in,
                              void* d_out, int out_size, void* d_ws, size_t ws_size,
                              hipStream_t stream) {
    const float* ue    = (const float*)d_in[0];
    const float* ie    = (const float*)d_in[1];
    const int*   rows  = (const int*)d_in[2];
    const int*   cols  = (const int*)d_in[3];
    const float* vals  = (const float*)d_in[4];
    const float* noise = (const float*)d_in[5];
    float* out = (float*)d_out;
    char*  ws  = (char*)d_ws;

    auto align16 = [](size_t x) { return (x + 15) & ~(size_t)15; };
    size_t off = 0;
    int*   rowptr   = (int*)(ws + off);  off = align16(off + (size_t)(N_CNT + 1) * 4);
    int*   keyptr   = (int*)(ws + off);  off = align16(off + KEYS_PAD * 4);
    int*   tileSums = (int*)(ws + off);  off = align16(off + (size_t)N_TILES2 * 4);
    int*   tileOffs = (int*)(ws + off);  off = align16(off + (size_t)N_TILES2 * 4);
    int2*  cpack    = (int2*)(ws + off); off = align16(off + (size_t)NNZ_CNT * 8);
    float* bufA     = (float*)(ws + off); off += (size_t)N_CNT * D_DIM * 4;
    (void)ws_size; (void)in_sizes; (void)n_in; (void)out_size;

    const size_t ND = (size_t)N_CNT * D_DIM;
    float* cl = out + ND;  // ego_cl region; doubles as layer-0 output / layer-1 input

    // ---- build col-block-sorted CSR via counting sort on (row, col>>12) ----
    hipMemsetAsync(keyptr, 0, KEYS_PAD * 4, stream);
    hist_key_kernel<<<(NNZ_CNT / 4 + 255) / 256, 256, 0, stream>>>(rows, cols, keyptr);
    key_scan1<<<N_TILES2, 256, 0, stream>>>(keyptr, tileSums);
    key_scan2<<<1, 256, 0, stream>>>(tileSums, tileOffs);
    key_scan3<<<N_TILES2, 256, 0, stream>>>(keyptr, tileOffs);
    rowptr_kernel<<<(N_CNT + 255) / 256, 256, 0, stream>>>(keyptr, rowptr);
    scatter_key_kernel<<<(NNZ_CNT / 4 + 255) / 256, 256, 0, stream>>>(rows, cols, vals,
                                                                      keyptr, cpack);

    // ---- 3 propagation layers (fused spmm + noise + accumulate) ----
    int blocks = (N_CNT + 15) / 16;
    layer_kernel<0><<<blocks, 256, 0, stream>>>(rowptr, cpack, nullptr,
                                                (const float4*)ue, (const float4*)ie,
                                                (const float4*)(noise + 0 * ND),
                                                (float4*)cl, (float4*)out);
    layer_kernel<1><<<blocks, 256, 0, stream>>>(rowptr, cpack, (const float4*)cl,
                                                nullptr, nullptr,
                                                (const float4*)(noise + 1 * ND),
                                                (float4*)bufA, (float4*)out);
    layer_kernel<2><<<blocks, 256, 0, stream>>>(rowptr, cpack, (const float4*)bufA,
                                                nullptr, nullptr,
                                                (const float4*)(noise + 2 * ND),
                                                nullptr, (float4*)out);
}